// Round 5
// baseline (486.034 us; speedup 1.0000x reference)
//
#include <hip/hip_runtime.h>
#include <math.h>
#include <stdint.h>

#define NE 8
#define ED 1024
#define FD 2048
#define NTOK 2048

typedef unsigned short u16;
typedef unsigned int u32;
typedef __attribute__((ext_vector_type(4))) float f32x4;
typedef __attribute__((ext_vector_type(8))) short s16x8;
typedef __attribute__((ext_vector_type(4))) unsigned int u32v4;

// ---------------- helpers ----------------

__device__ __forceinline__ u16 f2bf(float f) {
    u32 u = __builtin_bit_cast(u32, f);
    u32 r = u + 0x7fffu + ((u >> 16) & 1u);   // RNE
    return (u16)(r >> 16);
}

// pack 8 f32 -> 8 bf16 (k ascending, low half first)
__device__ __forceinline__ s16x8 pack8(const float* v) {
    union { s16x8 s; u32 w[4]; } u;
#pragma unroll
    for (int i = 0; i < 4; i++)
        u.w[i] = (u32)f2bf(v[2 * i]) | ((u32)f2bf(v[2 * i + 1]) << 16);
    return u.s;
}

// workspace layout (bytes)
#define WS_CNT 0u
#define WS_OFF 64u
#define WS_TOK 256u
#define WS_WT  65792u
#define WS_XB  131328u
#define WS_ACT 4325632u
#define WS_NEED 21102848u

// ---------------- router ----------------

__global__ __launch_bounds__(256) void k_router(
        const float* __restrict__ gin, const float* __restrict__ gk,
        int* __restrict__ cnt, int* __restrict__ tok, float* __restrict__ wl) {
    int lane = threadIdx.x & 63;
    int t = (blockIdx.x * 256 + threadIdx.x) >> 6;   // one wave per token
    if (t >= NTOK) return;
    const float* row = gin + (size_t)t * ED;
    float acc[NE];
#pragma unroll
    for (int e = 0; e < NE; e++) acc[e] = 0.f;
    for (int i = lane; i < ED; i += 64) {
        float v = row[i];
        const float* g = gk + i * NE;
#pragma unroll
        for (int e = 0; e < NE; e++) acc[e] = fmaf(v, g[e], acc[e]);
    }
#pragma unroll
    for (int e = 0; e < NE; e++) {
#pragma unroll
        for (int off = 32; off > 0; off >>= 1)
            acc[e] += __shfl_down(acc[e], off, 64);
    }
    if (lane == 0) {
        int b0 = 0; float v0 = acc[0];
#pragma unroll
        for (int e = 1; e < NE; e++) if (acc[e] > v0) { v0 = acc[e]; b0 = e; }
        int b1 = -1; float v1 = -3.4e38f;
#pragma unroll
        for (int e = 0; e < NE; e++) if (e != b0 && acc[e] > v1) { v1 = acc[e]; b1 = e; }
        float w0 = 1.f / (1.f + __expf(-v0));
        float w1 = 1.f / (1.f + __expf(-v1));
        int p0 = atomicAdd(&cnt[b0], 1);
        tok[b0 * NTOK + p0] = t; wl[b0 * NTOK + p0] = w0;
        int p1 = atomicAdd(&cnt[b1], 1);
        tok[b1 * NTOK + p1] = t; wl[b1 * NTOK + p1] = w1;
    }
}

__global__ void k_scan(const int* __restrict__ cnt, int* __restrict__ off) {
    if (threadIdx.x == 0 && blockIdx.x == 0) {
        int a = 0;
#pragma unroll
        for (int e = 0; e < NE; e++) { off[e] = a; a += (cnt[e] + 255) & ~255; }
        off[NE] = a;
    }
}

// ---------------- x -> bf16 ----------------

__global__ __launch_bounds__(256) void k_cvtx(const float4* __restrict__ x, uint2* __restrict__ xb) {
    int i = blockIdx.x * 256 + threadIdx.x;
    float4 v = x[i];
    uint2 o;
    o.x = (u32)f2bf(v.x) | ((u32)f2bf(v.y) << 16);
    o.y = (u32)f2bf(v.z) | ((u32)f2bf(v.w) << 16);
    xb[i] = o;
}

// ---------------- pass A: gate+up GEMM, gelu*up -> act (plain layout) -------
// BM=256, BN=64 per tensor. A: xb bf16 via swizzled LDS. B: f32 weights read
// DIRECTLY into MFMA B-fragments (8 dword loads, 64B-coalesced per quad),
// converted to bf16 in-register. No cvtw kernel, no B LDS.

__global__ __launch_bounds__(256, 2) void k_passA(
        const u16* __restrict__ xb, const float* __restrict__ wgf, const float* __restrict__ wuf,
        const int* __restrict__ cnt, const int* __restrict__ off,
        const int* __restrict__ tok, u16* __restrict__ act) {
    int flat = blockIdx.x;
    int nt = flat & 31; int r = flat >> 5; int e = r & 7; int mt = r >> 3;
    int c = cnt[e];
    if (mt * 256 >= c) return;
    int rmax = c - mt * 256; if (rmax > 256) rmax = 256;

    __shared__ u16 sA[256 * 64];      // 32 KB, row stride 64, 16B groups swizzled by (m&7)

    int tid = threadIdx.x;
    int lane = tid & 63, wv = tid >> 6;
    int wm = wv >> 1, wn = wv & 1;    // wave: 128m x 32n (per tensor)
    int col = lane & 15, quad = lane >> 4;
    int swz = col & 7;

    f32x4 zero = {0.f, 0.f, 0.f, 0.f};
    f32x4 ag[8][2], au[8][2];
#pragma unroll
    for (int i = 0; i < 8; i++)
#pragma unroll
        for (int j = 0; j < 2; j++) { ag[i][j] = zero; au[i][j] = zero; }

    // A staging: one row per thread
    int ridx = mt * 256 + tid; if (ridx > c - 1) ridx = c - 1;
    int trow = tok[e * NTOK + ridx];
    const u16* asrc = xb + (size_t)trow * ED;
    u16* adst = sA + tid * 64;
    int am7 = tid & 7;

    const float* wgB = wgf + (size_t)e * (ED * FD) + nt * 64 + wn * 32 + col;
    const float* wuB = wuf + (size_t)e * (ED * FD) + nt * 64 + wn * 32 + col;

    for (int kc = 0; kc < 16; kc++) {
        const u16* as = asrc + kc * 64;
        u32v4 pa[8];
#pragma unroll
        for (int j = 0; j < 8; j++) pa[j] = *(const u32v4*)(as + j * 8);
        __syncthreads();
#pragma unroll
        for (int j = 0; j < 8; j++)
            *(u32v4*)(adst + ((j ^ am7) << 3)) = pa[j];
        __syncthreads();
#pragma unroll
        for (int st = 0; st < 2; st++) {
            int poff = ((st * 4 + quad) ^ swz) * 8;
            s16x8 af[8];
#pragma unroll
            for (int mf = 0; mf < 8; mf++)
                af[mf] = *(const s16x8*)(sA + (wm * 128 + mf * 16 + col) * 64 + poff);
            size_t kbase = (size_t)(kc * 64 + st * 32 + quad * 8);
            // gate
#pragma unroll
            for (int nf = 0; nf < 2; nf++) {
                float bv[8];
#pragma unroll
                for (int j = 0; j < 8; j++) bv[j] = wgB[(kbase + j) * FD + nf * 16];
                s16x8 bf = pack8(bv);
#pragma unroll
                for (int mf = 0; mf < 8; mf++)
                    ag[mf][nf] = __builtin_amdgcn_mfma_f32_16x16x32_bf16(af[mf], bf, ag[mf][nf], 0, 0, 0);
            }
            // up
#pragma unroll
            for (int nf = 0; nf < 2; nf++) {
                float bv[8];
#pragma unroll
                for (int j = 0; j < 8; j++) bv[j] = wuB[(kbase + j) * FD + nf * 16];
                s16x8 bf = pack8(bv);
#pragma unroll
                for (int mf = 0; mf < 8; mf++)
                    au[mf][nf] = __builtin_amdgcn_mfma_f32_16x16x32_bf16(af[mf], bf, au[mf][nf], 0, 0, 0);
            }
        }
    }

    // epilogue: act = gelu_tanh(gate) * up -> plain [row][FD] bf16
    int rbase = off[e] + mt * 256;
#pragma unroll
    for (int mf = 0; mf < 8; mf++) {
#pragma unroll
        for (int reg = 0; reg < 4; reg++) {
            int m = wm * 128 + mf * 16 + quad * 4 + reg;
            if (m < rmax) {
                u16* arow = act + (size_t)(rbase + m) * FD + nt * 64 + wn * 32 + col;
#pragma unroll
                for (int nf = 0; nf < 2; nf++) {
                    float gv = ag[mf][nf][reg];
                    float uv = au[mf][nf][reg];
                    float z = 0.7978845608028654f * (gv + 0.044715f * gv * gv * gv);
                    float ez = __expf(-2.f * fabsf(z));
                    float th = (1.f - ez) / (1.f + ez);
                    th = (z < 0.f) ? -th : th;
                    float a = 0.5f * gv * (1.f + th) * uv;
                    arow[nf * 16] = f2bf(a);
                }
            }
        }
    }
}

// ---------------- pass B: down GEMM + weighted scatter ----------------
// BM=128, BN=64. A: act bf16 (contiguous rows) via swizzled LDS.
// B: f32 down_proj direct-to-fragment.

__global__ __launch_bounds__(256, 3) void k_passB(
        const u16* __restrict__ act, const float* __restrict__ wdf,
        const int* __restrict__ cnt, const int* __restrict__ off,
        const int* __restrict__ tok, const float* __restrict__ wl,
        const float* __restrict__ scale, float* __restrict__ out) {
    int flat = blockIdx.x;
    int nt = flat & 15; int r = flat >> 4; int e = r & 7; int mt = r >> 3;
    int c = cnt[e];
    if (mt * 128 >= c) return;
    int rmax = c - mt * 128; if (rmax > 128) rmax = 128;

    __shared__ u16 sA[128 * 64];      // 16 KB

    int tid = threadIdx.x;
    int lane = tid & 63, wv = tid >> 6;
    int wm = wv >> 1, wn = wv & 1;    // wave: 64m x 32n
    int col = lane & 15, quad = lane >> 4;
    int swz = col & 7;

    f32x4 zero = {0.f, 0.f, 0.f, 0.f};
    f32x4 acc[4][2];
#pragma unroll
    for (int i = 0; i < 4; i++)
#pragma unroll
        for (int j = 0; j < 2; j++) acc[i][j] = zero;

    int am = tid >> 1, ah = tid & 1;
    const u16* asrc = act + (size_t)(off[e] + mt * 128 + am) * FD + ah * 32;
    u16* adst = sA + am * 64;
    int am7 = am & 7;

    const float* wdB = wdf + (size_t)e * (FD * ED) + nt * 64 + wn * 32 + col;

    for (int kc = 0; kc < 32; kc++) {
        const u16* as = asrc + kc * 64;
        u32v4 pa[4];
#pragma unroll
        for (int j = 0; j < 4; j++) pa[j] = *(const u32v4*)(as + j * 8);
        __syncthreads();
#pragma unroll
        for (int j = 0; j < 4; j++)
            *(u32v4*)(adst + (((ah * 4 + j) ^ am7) << 3)) = pa[j];
        __syncthreads();
#pragma unroll
        for (int st = 0; st < 2; st++) {
            int poff = ((st * 4 + quad) ^ swz) * 8;
            s16x8 af[4];
#pragma unroll
            for (int mf = 0; mf < 4; mf++)
                af[mf] = *(const s16x8*)(sA + (wm * 64 + mf * 16 + col) * 64 + poff);
            size_t kbase = (size_t)(kc * 64 + st * 32 + quad * 8);
#pragma unroll
            for (int nf = 0; nf < 2; nf++) {
                float bv[8];
#pragma unroll
                for (int j = 0; j < 8; j++) bv[j] = wdB[(kbase + j) * ED + nf * 16];
                s16x8 bf = pack8(bv);
#pragma unroll
                for (int mf = 0; mf < 4; mf++)
                    acc[mf][nf] = __builtin_amdgcn_mfma_f32_16x16x32_bf16(af[mf], bf, acc[mf][nf], 0, 0, 0);
            }
        }
    }

    float sc = scale[e];
    int lbase = e * NTOK + mt * 128;
#pragma unroll
    for (int mf = 0; mf < 4; mf++) {
#pragma unroll
        for (int reg = 0; reg < 4; reg++) {
            int m = wm * 64 + mf * 16 + quad * 4 + reg;
            if (m < rmax) {
                int t = tok[lbase + m];
                float w = wl[lbase + m] * sc;
                float* orow = out + (size_t)t * ED + nt * 64 + wn * 32 + col;
#pragma unroll
                for (int nf = 0; nf < 2; nf++)
                    atomicAdd(orow + nf * 16, acc[mf][nf][reg] * w);
            }
        }
    }
}

// ---------------- launch ----------------

extern "C" void kernel_launch(void* const* d_in, const int* in_sizes, int n_in,
                              void* d_out, int out_size, void* d_ws, size_t ws_size,
                              hipStream_t stream) {
    const float* x   = (const float*)d_in[0];
    const float* gin = (const float*)d_in[1];
    const float* gk  = (const float*)d_in[2];
    const float* sc  = (const float*)d_in[3];
    const float* wgf = (const float*)d_in[4];
    const float* wuf = (const float*)d_in[5];
    const float* wdf = (const float*)d_in[6];
    float* out = (float*)d_out;

    if (ws_size < (size_t)WS_NEED) {
        hipMemsetAsync(d_out, 0, (size_t)out_size * sizeof(float), stream);
        return;
    }

    char* ws = (char*)d_ws;
    int*   cnt = (int*)(ws + WS_CNT);
    int*   off = (int*)(ws + WS_OFF);
    int*   tok = (int*)(ws + WS_TOK);
    float* wl  = (float*)(ws + WS_WT);
    u16*   xb  = (u16*)(ws + WS_XB);
    u16*   act = (u16*)(ws + WS_ACT);

    hipMemsetAsync(cnt, 0, 64, stream);
    hipMemsetAsync(d_out, 0, (size_t)out_size * sizeof(float), stream);

    k_router<<<dim3(512), dim3(256), 0, stream>>>(gin, gk, cnt, tok, wl);
    k_scan<<<dim3(1), dim3(64), 0, stream>>>(cnt, off);
    k_cvtx<<<dim3(2048), dim3(256), 0, stream>>>((const float4*)x, (uint2*)xb);
    k_passA<<<dim3(2048), dim3(256), 0, stream>>>(xb, wgf, wuf, cnt, off, tok, act);
    k_passB<<<dim3(2048), dim3(256), 0, stream>>>(act, wdf, cnt, off, tok, wl, sc, out);
}